// Round 3
// baseline (756.057 us; speedup 1.0000x reference)
//
#include <hip/hip_runtime.h>

#define NN 20000
#define EE 600000

typedef unsigned short u16;
typedef unsigned int u32;
typedef float f32x4 __attribute__((ext_vector_type(4)));
typedef u32 u32x4 __attribute__((ext_vector_type(4)));

__device__ __forceinline__ u16 f2bf(float f){
  u32 u = __float_as_uint(f);
  return (u16)((u + 0x7fffu + ((u>>16)&1u))>>16);
}
__device__ __forceinline__ float bf2f(u16 h){ return __uint_as_float(((u32)h)<<16); }

// jax.nn.gelu default (approximate=True, tanh form)
__device__ __forceinline__ float gelu_f(float x){
  float u = 0.7978845608028654f*(x + 0.044715f*x*x*x);
  float e = __expf(2.0f*u);
  return 0.5f*x*(2.0f - 2.0f/(e+1.0f));   // 0.5x(1+tanh(u)), overflow-safe
}

// ---------------------------------------------------------------------------
// LayerNorm x2: za = LN(x;g_att,b_att) (stride 512); z_mlp = LN(x;g_mlp,b_mlp)
// written directly into xf[0:512] (stride 576). One wave per row.
// ---------------------------------------------------------------------------
__global__ __launch_bounds__(256) void ln2_kernel(
    const float* __restrict__ x,
    const float* __restrict__ ga, const float* __restrict__ ba,
    const float* __restrict__ gm, const float* __restrict__ bm,
    u16* __restrict__ za, u16* __restrict__ xf, int N)
{
  int row = (blockIdx.x<<2) + (threadIdx.x>>6);
  int lane = threadIdx.x & 63;
  if(row >= N) return;
  const float* xp = x + ((size_t)row<<9) + (lane<<3);
  f32x4 v0 = *(const f32x4*)xp;
  f32x4 v1 = *(const f32x4*)(xp+4);
  float vals[8] = {v0[0],v0[1],v0[2],v0[3],v1[0],v1[1],v1[2],v1[3]};
  float s=0.f, qs=0.f;
#pragma unroll
  for(int i=0;i<8;i++){ s += vals[i]; qs = fmaf(vals[i],vals[i],qs); }
#pragma unroll
  for(int o=1;o<64;o<<=1){ s += __shfl_xor(s,o); qs += __shfl_xor(qs,o); }
  float mean = s*(1.f/512.f);
  float var  = qs*(1.f/512.f) - mean*mean;
  float rstd = rsqrtf(var + 1e-5f);
  int c0 = lane<<3;
#pragma unroll
  for(int i=0;i<8;i++){
    float zn = (vals[i]-mean)*rstd;
    za[((size_t)row<<9)+c0+i]  = f2bf(fmaf(zn, ga[c0+i], ba[c0+i]));
    xf[(size_t)row*576+c0+i]   = f2bf(fmaf(zn, gm[c0+i], bm[c0+i]));
  }
}

// ---------------------------------------------------------------------------
// Weight transpose via LDS tile: W[K][Nn] fp32 -> WT[Nn][Kpad] bf16, zero pad.
// Coalesced reads AND writes. grid = (Kpad/64, Nn/64), block 256.
// ---------------------------------------------------------------------------
__global__ __launch_bounds__(256) void wtt_kernel(
    const float* __restrict__ W, u16* __restrict__ WT, int K, int Nn, int Kpad)
{
  __shared__ u16 tile[64][65];
  const int k0 = blockIdx.x<<6, n0 = blockIdx.y<<6;
  const int tx = threadIdx.x & 63, ty = threadIdx.x >> 6;
#pragma unroll
  for(int i=0;i<16;i++){
    int r = (i<<2) + ty;                 // k within tile
    int gk = k0 + r;
    float v = (gk < K) ? W[(size_t)gk*Nn + n0 + tx] : 0.f;
    tile[r][tx] = f2bf(v);
  }
  __syncthreads();
#pragma unroll
  for(int i=0;i<16;i++){
    int r = (i<<2) + ty;                 // n within tile
    WT[(size_t)(n0 + r)*Kpad + k0 + tx] = tile[tx][r];
  }
}

// ---------------------------------------------------------------------------
// GEMM: C[M,N] = A[M,K](bf16,row-stride lda) @ B^T[N,K](bf16) + bias;
// optional gelu; optional residual (post-gelu); bf16 out. 128x128x64 tiles,
// MFMA 16x16x32, XOR-swizzled LDS, global_load_lds width 16.
// ---------------------------------------------------------------------------
__global__ __launch_bounds__(256) void gemm_bt(
    const u16* __restrict__ A, const u16* __restrict__ B,
    const float* __restrict__ bias, const u16* __restrict__ resid,
    u16* __restrict__ Cb, int M, int N, int K, int lda, int doGelu)
{
  __shared__ u16 As[128*64];
  __shared__ u16 Bs[128*64];
  const int tid  = threadIdx.x;
  const int wave = tid>>6, lane = tid&63;
  const int quad = lane>>4, l15 = lane&15;
  const int tileM = blockIdx.x<<7, tileN = blockIdx.y<<7;
  const int mhalf = (wave>>1)<<6, nhalf = (wave&1)<<6;
  f32x4 acc[4][4] = {};

  for(int k0=0; k0<K; k0+=64){
#pragma unroll
    for(int j=0;j<4;j++){
      const int c   = (((wave<<2)+j)<<6) + lane;   // LDS chunk this lane fills
      const int row = c>>3;
      const int cc  = (c&7) ^ (row&7);             // which logical k-chunk lands here
      int gr = tileM + row; gr = (gr < M) ? gr : (M-1);
      const u16* gp = A + (size_t)gr*lda + (size_t)(k0 + (cc<<3));
      __builtin_amdgcn_global_load_lds(
        (const __attribute__((address_space(1))) u32*)gp,
        (__attribute__((address_space(3))) u32*)(&As[((wave<<2)+j)<<9]),
        16, 0, 0);
    }
#pragma unroll
    for(int j=0;j<4;j++){
      const int c   = (((wave<<2)+j)<<6) + lane;
      const int row = c>>3;
      const int cc  = (c&7) ^ (row&7);
      const u16* gp = B + (size_t)(tileN + row)*K + (size_t)(k0 + (cc<<3));
      __builtin_amdgcn_global_load_lds(
        (const __attribute__((address_space(1))) u32*)gp,
        (__attribute__((address_space(3))) u32*)(&Bs[((wave<<2)+j)<<9]),
        16, 0, 0);
    }
    __syncthreads();
#pragma unroll
    for(int ks=0;ks<2;ks++){
      const int ccol = (ks<<2) + quad;             // logical 16B k-chunk index
      u32x4 af[4], bfr[4];
#pragma unroll
      for(int mi=0;mi<4;mi++){
        const int row = mhalf + (mi<<4) + l15;
        af[mi] = *(const u32x4*)&As[((row<<3) + (ccol ^ (row&7)))<<3];
      }
#pragma unroll
      for(int ni=0;ni<4;ni++){
        const int row = nhalf + (ni<<4) + l15;
        bfr[ni] = *(const u32x4*)&Bs[((row<<3) + (ccol ^ (row&7)))<<3];
      }
#pragma unroll
      for(int mi=0;mi<4;mi++)
#pragma unroll
        for(int ni=0;ni<4;ni++)
          asm("v_mfma_f32_16x16x32_bf16 %0, %1, %2, %0"
              : "+v"(acc[mi][ni]) : "v"(af[mi]), "v"(bfr[ni]));
    }
    __syncthreads();
  }

#pragma unroll
  for(int mi=0;mi<4;mi++){
#pragma unroll
    for(int reg=0;reg<4;reg++){
      const int gr = tileM + mhalf + (mi<<4) + (quad<<2) + reg;
      if(gr < M){
#pragma unroll
        for(int ni=0;ni<4;ni++){
          const int gc = tileN + nhalf + (ni<<4) + l15;
          float v = acc[mi][ni][reg] + bias[gc];
          if(doGelu) v = gelu_f(v);
          if(resid) v += bf2f(resid[(size_t)gr*N + gc]);
          Cb[(size_t)gr*N + gc] = f2bf(v);
        }
      }
    }
  }
}

// ---------------------------------------------------------------------------
// Edge counting-sort by destination row: histogram, scan, scatter.
// ---------------------------------------------------------------------------
__global__ __launch_bounds__(256) void hist_kernel(
    const int* __restrict__ ei, int* __restrict__ deg, int E)
{
  int e = blockIdx.x*256 + threadIdx.x;
  if(e < E) atomicAdd(&deg[ei[e]], 1);
}

// single-block exclusive scan over deg[0..N) -> rowptr & cursor; rowptr[N]=E
__global__ __launch_bounds__(1024) void scan_kernel(
    const int* __restrict__ deg, int* __restrict__ rowptr,
    int* __restrict__ cursor, int N)
{
  __shared__ int buf[1024];
  __shared__ int carry;
  const int tid = threadIdx.x;
  if(tid == 0) carry = 0;
  __syncthreads();
  for(int base = 0; base < N; base += 1024){
    int v = (base + tid < N) ? deg[base + tid] : 0;
    buf[tid] = v;
    __syncthreads();
#pragma unroll
    for(int off=1; off<1024; off<<=1){
      int t = (tid >= off) ? buf[tid-off] : 0;
      __syncthreads();
      buf[tid] += t;
      __syncthreads();
    }
    if(base + tid < N){
      int ex = buf[tid] - v + carry;
      rowptr[base + tid] = ex;
      cursor[base + tid] = ex;
    }
    __syncthreads();
    if(tid == 0) carry += buf[1023];
    __syncthreads();
  }
  if(tid == 0) rowptr[N] = carry;
}

__global__ __launch_bounds__(256) void scatter_kernel(
    const int* __restrict__ ei, const float* __restrict__ ab,
    int* __restrict__ cursor, int* __restrict__ cols,
    float* __restrict__ abs_, int E)
{
  int e = blockIdx.x*256 + threadIdx.x;
  if(e >= E) return;
  int r = ei[e];
  int p = atomicAdd(&cursor[r], 1);
  cols[p] = ei[EE + e];
  abs_[p] = ab[e];
}

// ---------------------------------------------------------------------------
// Per-node attention: one wave per node. q-row in registers; loop over the
// node's (sorted) edges gathering k-rows; softmax without max-subtraction
// (logits O(+-6)); accumulate denom & weighted pos in REGISTERS (no atomics);
// write att-pos directly into xf[512:536] and zeros into xf[536:576].
// qk layout: row n = [q(512) | k(512)] bf16.
// ---------------------------------------------------------------------------
__global__ __launch_bounds__(256) void node_att_kernel(
    const u16* __restrict__ qk, const int* __restrict__ rowptr,
    const int* __restrict__ cols, const float* __restrict__ abs_,
    const float* __restrict__ pos, u16* __restrict__ xf, int N)
{
  const int node = (blockIdx.x<<2) + (threadIdx.x>>6);
  const int lane = threadIdx.x & 63;
  if(node >= N) return;
  const int h = lane>>3, sub = lane&7;
  const u32x4 qv = *(const u32x4*)(qk + ((size_t)node<<10) + (lane<<3));
  const float posn = (sub<3) ? pos[node*3 + sub] : 0.f;
  const int j1 = rowptr[node+1];
  float den = 0.f, nm = 0.f;

  int j = rowptr[node];
  for(; j+1 < j1; j += 2){
    int c0 = cols[j], c1 = cols[j+1];
    u32x4 kv0 = *(const u32x4*)(qk + ((size_t)c0<<10) + 512 + (lane<<3));
    u32x4 kv1 = *(const u32x4*)(qk + ((size_t)c1<<10) + 512 + (lane<<3));
    float pv0 = (sub<3) ? pos[c0*3+sub] : 0.f;
    float pv1 = (sub<3) ? pos[c1*3+sub] : 0.f;
    float ab0 = abs_[j], ab1 = abs_[j+1];
    float s0=0.f, s1=0.f;
#pragma unroll
    for(int i=0;i<4;i++){
      float qa = __uint_as_float(qv[i]<<16), qb = __uint_as_float(qv[i]&0xffff0000u);
      s0 = fmaf(qa, __uint_as_float(kv0[i]<<16), s0);
      s0 = fmaf(qb, __uint_as_float(kv0[i]&0xffff0000u), s0);
      s1 = fmaf(qa, __uint_as_float(kv1[i]<<16), s1);
      s1 = fmaf(qb, __uint_as_float(kv1[i]&0xffff0000u), s1);
    }
    s0 += __shfl_xor(s0,1); s0 += __shfl_xor(s0,2); s0 += __shfl_xor(s0,4);
    s1 += __shfl_xor(s1,1); s1 += __shfl_xor(s1,2); s1 += __shfl_xor(s1,4);
    float p0 = __expf(fmaf(s0, 0.125f, ab0));
    float p1 = __expf(fmaf(s1, 0.125f, ab1));
    den += p0 + p1;
    nm = fmaf(p0, pv0, nm);
    nm = fmaf(p1, pv1, nm);
  }
  if(j < j1){
    int c0 = cols[j];
    u32x4 kv0 = *(const u32x4*)(qk + ((size_t)c0<<10) + 512 + (lane<<3));
    float pv0 = (sub<3) ? pos[c0*3+sub] : 0.f;
    float s0=0.f;
#pragma unroll
    for(int i=0;i<4;i++){
      s0 = fmaf(__uint_as_float(qv[i]<<16),        __uint_as_float(kv0[i]<<16), s0);
      s0 = fmaf(__uint_as_float(qv[i]&0xffff0000u),__uint_as_float(kv0[i]&0xffff0000u), s0);
    }
    s0 += __shfl_xor(s0,1); s0 += __shfl_xor(s0,2); s0 += __shfl_xor(s0,4);
    float p0 = __expf(fmaf(s0, 0.125f, abs_[j]));
    den += p0;
    nm = fmaf(p0, pv0, nm);
  }

  u16* xp = xf + (size_t)node*576;
  if(sub < 3){
    float a = (den > 0.f) ? nm/den : 0.f;
    xp[512 + h*3 + sub] = f2bf(a - posn);
  } else {
    xp[536 + h*5 + (sub-3)] = 0;   // pad cols 536..575
  }
}

// ---------------------------------------------------------------------------
// energy[n] = h2[n,:] @ W[:,1] + b ; one wave per row
// ---------------------------------------------------------------------------
__global__ __launch_bounds__(256) void energy_kernel(
    const u16* __restrict__ h2, const float* __restrict__ W,
    const float* __restrict__ b, float* __restrict__ out, int N)
{
  int row = (blockIdx.x<<2) + (threadIdx.x>>6);
  int lane = threadIdx.x & 63;
  if(row >= N) return;
  const u16* hp = h2 + ((size_t)row<<10) + (lane<<4);
  const float* wp = W + (lane<<4);
  u32x4 a0 = *(const u32x4*)hp;
  u32x4 a1 = *(const u32x4*)(hp+8);
  float hv[16];
#pragma unroll
  for(int i=0;i<4;i++){
    hv[2*i]   = __uint_as_float(a0[i]<<16);
    hv[2*i+1] = __uint_as_float(a0[i]&0xffff0000u);
    hv[8+2*i]   = __uint_as_float(a1[i]<<16);
    hv[8+2*i+1] = __uint_as_float(a1[i]&0xffff0000u);
  }
  float s = 0.f;
#pragma unroll
  for(int i=0;i<16;i++) s = fmaf(hv[i], wp[i], s);
#pragma unroll
  for(int o=1;o<64;o<<=1) s += __shfl_xor(s,o);
  if(lane==0) out[row] = s + b[0];
}

// ---------------------------------------------------------------------------
// forces[n,c] = h2f[n,:] @ W[:,c] + b[c] ; one wave per row, 3 accumulators
// ---------------------------------------------------------------------------
__global__ __launch_bounds__(256) void forces_kernel(
    const u16* __restrict__ h2, const float* __restrict__ W,
    const float* __restrict__ b, float* __restrict__ out, int N)
{
  int row = (blockIdx.x<<2) + (threadIdx.x>>6);
  int lane = threadIdx.x & 63;
  if(row >= N) return;
  const u16* hp = h2 + ((size_t)row<<10) + (lane<<4);
  const float* wp = W + (size_t)(lane<<4)*3;
  u32x4 a0 = *(const u32x4*)hp;
  u32x4 a1 = *(const u32x4*)(hp+8);
  float hv[16];
#pragma unroll
  for(int i=0;i<4;i++){
    hv[2*i]   = __uint_as_float(a0[i]<<16);
    hv[2*i+1] = __uint_as_float(a0[i]&0xffff0000u);
    hv[8+2*i]   = __uint_as_float(a1[i]<<16);
    hv[8+2*i+1] = __uint_as_float(a1[i]&0xffff0000u);
  }
  float s0=0.f, s1=0.f, s2=0.f;
#pragma unroll
  for(int i=0;i<16;i++){
    float h = hv[i];
    s0 = fmaf(h, wp[3*i+0], s0);
    s1 = fmaf(h, wp[3*i+1], s1);
    s2 = fmaf(h, wp[3*i+2], s2);
  }
#pragma unroll
  for(int o=1;o<64;o<<=1){ s0 += __shfl_xor(s0,o); s1 += __shfl_xor(s1,o); s2 += __shfl_xor(s2,o); }
  if(lane==0){
    out[(size_t)row*3+0] = s0 + b[0];
    out[(size_t)row*3+1] = s1 + b[1];
    out[(size_t)row*3+2] = s2 + b[2];
  }
}

// ---------------------------------------------------------------------------
extern "C" void kernel_launch(void* const* d_in, const int* in_sizes, int n_in,
                              void* d_out, int out_size, void* d_ws, size_t ws_size,
                              hipStream_t stream)
{
  (void)in_sizes; (void)n_in; (void)out_size; (void)ws_size;
  const float* x    = (const float*)d_in[0];
  const int*   ei   = (const int*)d_in[1];
  const float* ab   = (const float*)d_in[2];
  const float* pos  = (const float*)d_in[3];
  const float* g_att= (const float*)d_in[5];
  const float* b_att= (const float*)d_in[6];
  const float* g_mlp= (const float*)d_in[7];
  const float* b_mlp= (const float*)d_in[8];
  const float* Wq   = (const float*)d_in[9];  const float* bq  = (const float*)d_in[10];
  const float* Wk   = (const float*)d_in[11]; const float* bk  = (const float*)d_in[12];
  const float* WeI  = (const float*)d_in[13]; const float* beI = (const float*)d_in[14];
  const float* WeH  = (const float*)d_in[15]; const float* beH = (const float*)d_in[16];
  const float* WeO  = (const float*)d_in[17]; const float* beO = (const float*)d_in[18];
  const float* WfI  = (const float*)d_in[19]; const float* bfI = (const float*)d_in[20];
  const float* WfH  = (const float*)d_in[21]; const float* bfH = (const float*)d_in[22];
  const float* WfO  = (const float*)d_in[23]; const float* bfO = (const float*)d_in[24];

  char* w = (char*)d_ws;
  size_t off = 0;
  auto alloc = [&](size_t bytes) -> void* {
    void* p = w + off; off += (bytes + 255) & ~(size_t)255; return p;
  };
  u16* zatt = (u16*)alloc((size_t)NN*512*2);
  u16* qk   = (u16*)alloc((size_t)NN*1024*2);  // [q|k] per row; reused as h1
  u16* h1   = qk;
  u16* h2   = (u16*)alloc((size_t)NN*1024*2);
  u16* xf   = (u16*)alloc((size_t)NN*576*2);   // [z_mlp(512) | att(24) | 0(40)]
  u16* wqkT = (u16*)alloc((size_t)1024*512*2);
  u16* weIT = (u16*)alloc((size_t)1024*512*2);
  u16* weHT = (u16*)alloc((size_t)1024*1024*2);
  u16* wfIT = (u16*)alloc((size_t)1024*576*2);
  u16* wfHT = (u16*)alloc((size_t)1024*1024*2);
  float* bqk    = (float*)alloc((size_t)1024*4);
  int*   deg    = (int*)alloc((size_t)NN*4);
  int*   rowptr = (int*)alloc((size_t)(NN+1)*4);
  int*   cursor = (int*)alloc((size_t)NN*4);
  int*   cols   = (int*)alloc((size_t)EE*4);
  float* absrt  = (float*)alloc((size_t)EE*4);

  hipMemsetAsync(deg, 0, (size_t)NN*4, stream);
  hipMemcpyAsync(bqk,       bq, 512*4, hipMemcpyDeviceToDevice, stream);
  hipMemcpyAsync(bqk + 512, bk, 512*4, hipMemcpyDeviceToDevice, stream);

  // weights -> bf16 transposed [N][Kpad], coalesced via LDS tiles
  wtt_kernel<<<dim3(512/64, 512/64),256,0,stream>>>(Wq, wqkT,           512, 512, 512);
  wtt_kernel<<<dim3(512/64, 512/64),256,0,stream>>>(Wk, wqkT + 512*512, 512, 512, 512);
  wtt_kernel<<<dim3(512/64, 1024/64),256,0,stream>>>(WeI, weIT, 512, 1024, 512);
  wtt_kernel<<<dim3(1024/64,1024/64),256,0,stream>>>(WeH, weHT, 1024, 1024, 1024);
  wtt_kernel<<<dim3(576/64, 1024/64),256,0,stream>>>(WfI, wfIT, 536, 1024, 576);
  wtt_kernel<<<dim3(1024/64,1024/64),256,0,stream>>>(WfH, wfHT, 1024, 1024, 1024);

  ln2_kernel<<<dim3((NN+3)/4),256,0,stream>>>(x, g_att,b_att, g_mlp,b_mlp, zatt, xf, NN);

  // counting sort of edges by destination (row) node
  hist_kernel   <<<dim3((EE+255)/256),256,0,stream>>>(ei, deg, EE);
  scan_kernel   <<<1,1024,0,stream>>>(deg, rowptr, cursor, NN);
  scatter_kernel<<<dim3((EE+255)/256),256,0,stream>>>(ei, ab, cursor, cols, absrt, EE);

  // fused Q+K projection: row n of qk = [q(512) | k(512)]
  dim3 gQK((NN+127)/128, 1024/128);
  gemm_bt<<<gQK,256,0,stream>>>(zatt, wqkT, bqk, nullptr, qk, NN, 1024, 512, 512, 0);

  node_att_kernel<<<dim3((NN+3)/4),256,0,stream>>>(qk, rowptr, cols, absrt, pos, xf, NN);

  dim3 gH((NN+127)/128, 1024/128);
  // energy path (h1 overwrites qk — q,k dead after node_att)
  gemm_bt<<<gH,256,0,stream>>>(xf, weIT, beI, nullptr, h1, NN, 1024, 512, 576, 1);
  gemm_bt<<<gH,256,0,stream>>>(h1, weHT, beH, h1,      h2, NN, 1024, 1024, 1024, 1);
  energy_kernel<<<dim3((NN+3)/4),256,0,stream>>>(h2, WeO, beO, (float*)d_out, NN);

  // forces path
  gemm_bt<<<gH,256,0,stream>>>(xf, wfIT, bfI, nullptr, h1, NN, 1024, 576, 576, 1);
  gemm_bt<<<gH,256,0,stream>>>(h1, wfHT, bfH, h1,      h2, NN, 1024, 1024, 1024, 1);
  forces_kernel<<<dim3((NN+3)/4),256,0,stream>>>(h2, WfO, bfO, (float*)d_out + NN, NN);
}

// Round 4
// 731.794 us; speedup vs baseline: 1.0332x; 1.0332x over previous
//
#include <hip/hip_runtime.h>

#define NN 20000
#define EE 600000

typedef unsigned short u16;
typedef unsigned int u32;
typedef float f32x4 __attribute__((ext_vector_type(4)));
typedef u32 u32x4 __attribute__((ext_vector_type(4)));

__device__ __forceinline__ u16 f2bf(float f){
  u32 u = __float_as_uint(f);
  return (u16)((u + 0x7fffu + ((u>>16)&1u))>>16);
}
__device__ __forceinline__ float bf2f(u16 h){ return __uint_as_float(((u32)h)<<16); }

// jax.nn.gelu default (approximate=True, tanh form)
__device__ __forceinline__ float gelu_f(float x){
  float u = 0.7978845608028654f*(x + 0.044715f*x*x*x);
  float e = __expf(2.0f*u);
  return 0.5f*x*(2.0f - 2.0f/(e+1.0f));   // 0.5x(1+tanh(u)), overflow-safe
}

// ---------------------------------------------------------------------------
// LayerNorm x2: za = LN(x;g_att,b_att) (stride 512); z_mlp = LN(x;g_mlp,b_mlp)
// written directly into xf[0:512] (stride 576). One wave per row.
// ---------------------------------------------------------------------------
__global__ __launch_bounds__(256) void ln2_kernel(
    const float* __restrict__ x,
    const float* __restrict__ ga, const float* __restrict__ ba,
    const float* __restrict__ gm, const float* __restrict__ bm,
    u16* __restrict__ za, u16* __restrict__ xf, int N)
{
  int row = (blockIdx.x<<2) + (threadIdx.x>>6);
  int lane = threadIdx.x & 63;
  if(row >= N) return;
  const float* xp = x + ((size_t)row<<9) + (lane<<3);
  f32x4 v0 = *(const f32x4*)xp;
  f32x4 v1 = *(const f32x4*)(xp+4);
  float vals[8] = {v0[0],v0[1],v0[2],v0[3],v1[0],v1[1],v1[2],v1[3]};
  float s=0.f, qs=0.f;
#pragma unroll
  for(int i=0;i<8;i++){ s += vals[i]; qs = fmaf(vals[i],vals[i],qs); }
#pragma unroll
  for(int o=1;o<64;o<<=1){ s += __shfl_xor(s,o); qs += __shfl_xor(qs,o); }
  float mean = s*(1.f/512.f);
  float var  = qs*(1.f/512.f) - mean*mean;
  float rstd = rsqrtf(var + 1e-5f);
  int c0 = lane<<3;
#pragma unroll
  for(int i=0;i<8;i++){
    float zn = (vals[i]-mean)*rstd;
    za[((size_t)row<<9)+c0+i]  = f2bf(fmaf(zn, ga[c0+i], ba[c0+i]));
    xf[(size_t)row*576+c0+i]   = f2bf(fmaf(zn, gm[c0+i], bm[c0+i]));
  }
}

// ---------------------------------------------------------------------------
// Weight transpose via LDS tile: W[K][Nn] fp32 -> WT[Nn][Kpad] bf16, zero pad.
// Coalesced reads AND writes. grid = (Kpad/64, Nn/64), block 256.
// ---------------------------------------------------------------------------
__global__ __launch_bounds__(256) void wtt_kernel(
    const float* __restrict__ W, u16* __restrict__ WT, int K, int Nn, int Kpad)
{
  __shared__ u16 tile[64][65];
  const int k0 = blockIdx.x<<6, n0 = blockIdx.y<<6;
  const int tx = threadIdx.x & 63, ty = threadIdx.x >> 6;
#pragma unroll
  for(int i=0;i<16;i++){
    int r = (i<<2) + ty;                 // k within tile
    int gk = k0 + r;
    float v = (gk < K) ? W[(size_t)gk*Nn + n0 + tx] : 0.f;
    tile[r][tx] = f2bf(v);
  }
  __syncthreads();
#pragma unroll
  for(int i=0;i<16;i++){
    int r = (i<<2) + ty;                 // n within tile
    WT[(size_t)(n0 + r)*Kpad + k0 + tx] = tile[tx][r];
  }
}

// ---------------------------------------------------------------------------
// GEMM: C[M,N] = A[M,K](bf16,row-stride lda) @ B^T[N,K](bf16) + bias;
// optional gelu; optional residual (post-gelu); bf16 out. 128x128x64 tiles,
// MFMA 16x16x32, XOR-swizzled LDS, global_load_lds width 16.
// blockIdx.x = N-tile (FAST) so the 8 consecutive blocks share one A-tile ->
// A served from L2/L3 instead of 4.5x HBM re-fetch.
// ---------------------------------------------------------------------------
__global__ __launch_bounds__(256) void gemm_bt(
    const u16* __restrict__ A, const u16* __restrict__ B,
    const float* __restrict__ bias, const u16* __restrict__ resid,
    u16* __restrict__ Cb, int M, int N, int K, int lda, int doGelu)
{
  __shared__ u16 As[128*64];
  __shared__ u16 Bs[128*64];
  const int tid  = threadIdx.x;
  const int wave = tid>>6, lane = tid&63;
  const int quad = lane>>4, l15 = lane&15;
  const int tileM = blockIdx.y<<7, tileN = blockIdx.x<<7;
  const int mhalf = (wave>>1)<<6, nhalf = (wave&1)<<6;
  f32x4 acc[4][4] = {};

  for(int k0=0; k0<K; k0+=64){
#pragma unroll
    for(int j=0;j<4;j++){
      const int c   = (((wave<<2)+j)<<6) + lane;   // LDS chunk this lane fills
      const int row = c>>3;
      const int cc  = (c&7) ^ (row&7);             // which logical k-chunk lands here
      int gr = tileM + row; gr = (gr < M) ? gr : (M-1);
      const u16* gp = A + (size_t)gr*lda + (size_t)(k0 + (cc<<3));
      __builtin_amdgcn_global_load_lds(
        (const __attribute__((address_space(1))) u32*)gp,
        (__attribute__((address_space(3))) u32*)(&As[((wave<<2)+j)<<9]),
        16, 0, 0);
    }
#pragma unroll
    for(int j=0;j<4;j++){
      const int c   = (((wave<<2)+j)<<6) + lane;
      const int row = c>>3;
      const int cc  = (c&7) ^ (row&7);
      const u16* gp = B + (size_t)(tileN + row)*K + (size_t)(k0 + (cc<<3));
      __builtin_amdgcn_global_load_lds(
        (const __attribute__((address_space(1))) u32*)gp,
        (__attribute__((address_space(3))) u32*)(&Bs[((wave<<2)+j)<<9]),
        16, 0, 0);
    }
    __syncthreads();
#pragma unroll
    for(int ks=0;ks<2;ks++){
      const int ccol = (ks<<2) + quad;             // logical 16B k-chunk index
      u32x4 af[4], bfr[4];
#pragma unroll
      for(int mi=0;mi<4;mi++){
        const int row = mhalf + (mi<<4) + l15;
        af[mi] = *(const u32x4*)&As[((row<<3) + (ccol ^ (row&7)))<<3];
      }
#pragma unroll
      for(int ni=0;ni<4;ni++){
        const int row = nhalf + (ni<<4) + l15;
        bfr[ni] = *(const u32x4*)&Bs[((row<<3) + (ccol ^ (row&7)))<<3];
      }
#pragma unroll
      for(int mi=0;mi<4;mi++)
#pragma unroll
        for(int ni=0;ni<4;ni++)
          asm("v_mfma_f32_16x16x32_bf16 %0, %1, %2, %0"
              : "+v"(acc[mi][ni]) : "v"(af[mi]), "v"(bfr[ni]));
    }
    __syncthreads();
  }

#pragma unroll
  for(int mi=0;mi<4;mi++){
#pragma unroll
    for(int reg=0;reg<4;reg++){
      const int gr = tileM + mhalf + (mi<<4) + (quad<<2) + reg;
      if(gr < M){
#pragma unroll
        for(int ni=0;ni<4;ni++){
          const int gc = tileN + nhalf + (ni<<4) + l15;
          float v = acc[mi][ni][reg] + bias[gc];
          if(doGelu) v = gelu_f(v);
          if(resid) v += bf2f(resid[(size_t)gr*N + gc]);
          Cb[(size_t)gr*N + gc] = f2bf(v);
        }
      }
    }
  }
}

// ---------------------------------------------------------------------------
// Edge counting-sort by destination row: histogram, scan, scatter.
// ---------------------------------------------------------------------------
__global__ __launch_bounds__(256) void hist_kernel(
    const int* __restrict__ ei, int* __restrict__ deg, int E)
{
  int e = blockIdx.x*256 + threadIdx.x;
  if(e < E) atomicAdd(&deg[ei[e]], 1);
}

// single-block exclusive scan, shuffle-based (2 barriers per 1024 chunk)
__global__ __launch_bounds__(1024) void scan_kernel(
    const int* __restrict__ deg, int* __restrict__ rowptr,
    int* __restrict__ cursor, int N)
{
  __shared__ int wsum[16];
  __shared__ int carry_s;
  const int tid = threadIdx.x, lane = tid & 63, wid = tid >> 6;
  if(tid == 0) carry_s = 0;
  __syncthreads();
  for(int base = 0; base < N; base += 1024){
    int idx = base + tid;
    int v = (idx < N) ? deg[idx] : 0;
    int s = v;                                   // inclusive wave scan
#pragma unroll
    for(int o=1;o<64;o<<=1){ int t = __shfl_up(s,o); if(lane>=o) s += t; }
    if(lane==63) wsum[wid] = s;
    __syncthreads();
    if(wid==0 && lane<16){
      int ws = wsum[lane];
      int t = ws;
#pragma unroll
      for(int o=1;o<16;o<<=1){ int u = __shfl_up(t,o); if(lane>=o) t += u; }
      wsum[lane] = t - ws;                       // exclusive prefix of wave sums
    }
    __syncthreads();
    int ex = s - v + wsum[wid] + carry_s;
    if(idx < N){ rowptr[idx] = ex; cursor[idx] = ex; }
    __syncthreads();                             // all read carry_s before update
    if(tid == 1023) carry_s += wsum[15] + s;     // total of this chunk
  }
  __syncthreads();
  if(tid == 0) rowptr[N] = carry_s;
}

__global__ __launch_bounds__(256) void scatter_kernel(
    const int* __restrict__ ei, const float* __restrict__ ab,
    int* __restrict__ cursor, int* __restrict__ cols,
    float* __restrict__ abs_, int E)
{
  int e = blockIdx.x*256 + threadIdx.x;
  if(e >= E) return;
  int r = ei[e];
  int p = atomicAdd(&cursor[r], 1);
  cols[p] = ei[EE + e];
  abs_[p] = ab[e];
}

// ---------------------------------------------------------------------------
// Per-node attention: one wave per node. q-row in registers; loop over the
// node's (sorted) edges gathering k-rows; softmax without max-subtraction
// (logits O(+-6)); denom & weighted pos in REGISTERS (no atomics);
// write att-pos into xf[512:536] and zeros into xf[536:576].
// 4 edges in flight per iteration for memory-level parallelism.
// qk layout: row n = [q(512) | k(512)] bf16.
// ---------------------------------------------------------------------------
__global__ __launch_bounds__(256) void node_att_kernel(
    const u16* __restrict__ qk, const int* __restrict__ rowptr,
    const int* __restrict__ cols, const float* __restrict__ abs_,
    const float* __restrict__ pos, u16* __restrict__ xf, int N)
{
  const int node = (blockIdx.x<<2) + (threadIdx.x>>6);
  const int lane = threadIdx.x & 63;
  if(node >= N) return;
  const int h = lane>>3, sub = lane&7;
  const u32x4 qv = *(const u32x4*)(qk + ((size_t)node<<10) + (lane<<3));
  const float posn = (sub<3) ? pos[node*3 + sub] : 0.f;
  const int j1 = rowptr[node+1];
  float den = 0.f, nm = 0.f;

  int j = rowptr[node];
  for(; j+3 < j1; j += 4){
    int c[4]; float abv[4], pv[4]; u32x4 kv[4];
#pragma unroll
    for(int t=0;t<4;t++){ c[t] = cols[j+t]; abv[t] = abs_[j+t]; }
#pragma unroll
    for(int t=0;t<4;t++){
      kv[t] = *(const u32x4*)(qk + ((size_t)c[t]<<10) + 512 + (lane<<3));
      pv[t] = (sub<3) ? pos[c[t]*3+sub] : 0.f;
    }
#pragma unroll
    for(int t=0;t<4;t++){
      float s = 0.f;
#pragma unroll
      for(int i=0;i<4;i++){
        s = fmaf(__uint_as_float(qv[i]<<16),         __uint_as_float(kv[t][i]<<16), s);
        s = fmaf(__uint_as_float(qv[i]&0xffff0000u), __uint_as_float(kv[t][i]&0xffff0000u), s);
      }
      s += __shfl_xor(s,1); s += __shfl_xor(s,2); s += __shfl_xor(s,4);
      float p = __expf(fmaf(s, 0.125f, abv[t]));
      den += p;
      nm = fmaf(p, pv[t], nm);
    }
  }
  for(; j < j1; j++){
    int c0 = cols[j];
    u32x4 kv0 = *(const u32x4*)(qk + ((size_t)c0<<10) + 512 + (lane<<3));
    float pv0 = (sub<3) ? pos[c0*3+sub] : 0.f;
    float s0=0.f;
#pragma unroll
    for(int i=0;i<4;i++){
      s0 = fmaf(__uint_as_float(qv[i]<<16),        __uint_as_float(kv0[i]<<16), s0);
      s0 = fmaf(__uint_as_float(qv[i]&0xffff0000u),__uint_as_float(kv0[i]&0xffff0000u), s0);
    }
    s0 += __shfl_xor(s0,1); s0 += __shfl_xor(s0,2); s0 += __shfl_xor(s0,4);
    float p0 = __expf(fmaf(s0, 0.125f, abs_[j]));
    den += p0;
    nm = fmaf(p0, pv0, nm);
  }

  u16* xp = xf + (size_t)node*576;
  if(sub < 3){
    float a = (den > 0.f) ? nm/den : 0.f;
    xp[512 + h*3 + sub] = f2bf(a - posn);
  } else {
    xp[536 + h*5 + (sub-3)] = 0;   // pad cols 536..575
  }
}

// ---------------------------------------------------------------------------
// energy[n] = h2[n,:] @ W[:,1] + b ; one wave per row
// ---------------------------------------------------------------------------
__global__ __launch_bounds__(256) void energy_kernel(
    const u16* __restrict__ h2, const float* __restrict__ W,
    const float* __restrict__ b, float* __restrict__ out, int N)
{
  int row = (blockIdx.x<<2) + (threadIdx.x>>6);
  int lane = threadIdx.x & 63;
  if(row >= N) return;
  const u16* hp = h2 + ((size_t)row<<10) + (lane<<4);
  const float* wp = W + (lane<<4);
  u32x4 a0 = *(const u32x4*)hp;
  u32x4 a1 = *(const u32x4*)(hp+8);
  float hv[16];
#pragma unroll
  for(int i=0;i<4;i++){
    hv[2*i]   = __uint_as_float(a0[i]<<16);
    hv[2*i+1] = __uint_as_float(a0[i]&0xffff0000u);
    hv[8+2*i]   = __uint_as_float(a1[i]<<16);
    hv[8+2*i+1] = __uint_as_float(a1[i]&0xffff0000u);
  }
  float s = 0.f;
#pragma unroll
  for(int i=0;i<16;i++) s = fmaf(hv[i], wp[i], s);
#pragma unroll
  for(int o=1;o<64;o<<=1) s += __shfl_xor(s,o);
  if(lane==0) out[row] = s + b[0];
}

// ---------------------------------------------------------------------------
// forces[n,c] = h2f[n,:] @ W[:,c] + b[c] ; one wave per row, 3 accumulators
// ---------------------------------------------------------------------------
__global__ __launch_bounds__(256) void forces_kernel(
    const u16* __restrict__ h2, const float* __restrict__ W,
    const float* __restrict__ b, float* __restrict__ out, int N)
{
  int row = (blockIdx.x<<2) + (threadIdx.x>>6);
  int lane = threadIdx.x & 63;
  if(row >= N) return;
  const u16* hp = h2 + ((size_t)row<<10) + (lane<<4);
  const float* wp = W + (size_t)(lane<<4)*3;
  u32x4 a0 = *(const u32x4*)hp;
  u32x4 a1 = *(const u32x4*)(hp+8);
  float hv[16];
#pragma unroll
  for(int i=0;i<4;i++){
    hv[2*i]   = __uint_as_float(a0[i]<<16);
    hv[2*i+1] = __uint_as_float(a0[i]&0xffff0000u);
    hv[8+2*i]   = __uint_as_float(a1[i]<<16);
    hv[8+2*i+1] = __uint_as_float(a1[i]&0xffff0000u);
  }
  float s0=0.f, s1=0.f, s2=0.f;
#pragma unroll
  for(int i=0;i<16;i++){
    float h = hv[i];
    s0 = fmaf(h, wp[3*i+0], s0);
    s1 = fmaf(h, wp[3*i+1], s1);
    s2 = fmaf(h, wp[3*i+2], s2);
  }
#pragma unroll
  for(int o=1;o<64;o<<=1){ s0 += __shfl_xor(s0,o); s1 += __shfl_xor(s1,o); s2 += __shfl_xor(s2,o); }
  if(lane==0){
    out[(size_t)row*3+0] = s0 + b[0];
    out[(size_t)row*3+1] = s1 + b[1];
    out[(size_t)row*3+2] = s2 + b[2];
  }
}

// ---------------------------------------------------------------------------
extern "C" void kernel_launch(void* const* d_in, const int* in_sizes, int n_in,
                              void* d_out, int out_size, void* d_ws, size_t ws_size,
                              hipStream_t stream)
{
  (void)in_sizes; (void)n_in; (void)out_size; (void)ws_size;
  const float* x    = (const float*)d_in[0];
  const int*   ei   = (const int*)d_in[1];
  const float* ab   = (const float*)d_in[2];
  const float* pos  = (const float*)d_in[3];
  const float* g_att= (const float*)d_in[5];
  const float* b_att= (const float*)d_in[6];
  const float* g_mlp= (const float*)d_in[7];
  const float* b_mlp= (const float*)d_in[8];
  const float* Wq   = (const float*)d_in[9];  const float* bq  = (const float*)d_in[10];
  const float* Wk   = (const float*)d_in[11]; const float* bk  = (const float*)d_in[12];
  const float* WeI  = (const float*)d_in[13]; const float* beI = (const float*)d_in[14];
  const float* WeH  = (const float*)d_in[15]; const float* beH = (const float*)d_in[16];
  const float* WeO  = (const float*)d_in[17]; const float* beO = (const float*)d_in[18];
  const float* WfI  = (const float*)d_in[19]; const float* bfI = (const float*)d_in[20];
  const float* WfH  = (const float*)d_in[21]; const float* bfH = (const float*)d_in[22];
  const float* WfO  = (const float*)d_in[23]; const float* bfO = (const float*)d_in[24];

  char* w = (char*)d_ws;
  size_t off = 0;
  auto alloc = [&](size_t bytes) -> void* {
    void* p = w + off; off += (bytes + 255) & ~(size_t)255; return p;
  };
  u16* zatt = (u16*)alloc((size_t)NN*512*2);
  u16* qk   = (u16*)alloc((size_t)NN*1024*2);  // [q|k] per row; reused as h1
  u16* h1   = qk;
  u16* h2   = (u16*)alloc((size_t)NN*1024*2);
  u16* xf   = (u16*)alloc((size_t)NN*576*2);   // [z_mlp(512) | att(24) | 0(40)]
  u16* wqkT = (u16*)alloc((size_t)1024*512*2);
  u16* weIT = (u16*)alloc((size_t)1024*512*2);
  u16* weHT = (u16*)alloc((size_t)1024*1024*2);
  u16* wfIT = (u16*)alloc((size_t)1024*576*2);
  u16* wfHT = (u16*)alloc((size_t)1024*1024*2);
  float* bqk    = (float*)alloc((size_t)1024*4);
  int*   deg    = (int*)alloc((size_t)NN*4);
  int*   rowptr = (int*)alloc((size_t)(NN+1)*4);
  int*   cursor = (int*)alloc((size_t)NN*4);
  int*   cols   = (int*)alloc((size_t)EE*4);
  float* absrt  = (float*)alloc((size_t)EE*4);

  hipMemsetAsync(deg, 0, (size_t)NN*4, stream);
  hipMemcpyAsync(bqk,       bq, 512*4, hipMemcpyDeviceToDevice, stream);
  hipMemcpyAsync(bqk + 512, bk, 512*4, hipMemcpyDeviceToDevice, stream);

  // weights -> bf16 transposed [N][Kpad], coalesced via LDS tiles
  wtt_kernel<<<dim3(512/64, 512/64),256,0,stream>>>(Wq, wqkT,           512, 512, 512);
  wtt_kernel<<<dim3(512/64, 512/64),256,0,stream>>>(Wk, wqkT + 512*512, 512, 512, 512);
  wtt_kernel<<<dim3(512/64, 1024/64),256,0,stream>>>(WeI, weIT, 512, 1024, 512);
  wtt_kernel<<<dim3(1024/64,1024/64),256,0,stream>>>(WeH, weHT, 1024, 1024, 1024);
  wtt_kernel<<<dim3(576/64, 1024/64),256,0,stream>>>(WfI, wfIT, 536, 1024, 576);
  wtt_kernel<<<dim3(1024/64,1024/64),256,0,stream>>>(WfH, wfHT, 1024, 1024, 1024);

  ln2_kernel<<<dim3((NN+3)/4),256,0,stream>>>(x, g_att,b_att, g_mlp,b_mlp, zatt, xf, NN);

  // counting sort of edges by destination (row) node
  hist_kernel   <<<dim3((EE+255)/256),256,0,stream>>>(ei, deg, EE);
  scan_kernel   <<<1,1024,0,stream>>>(deg, rowptr, cursor, NN);
  scatter_kernel<<<dim3((EE+255)/256),256,0,stream>>>(ei, ab, cursor, cols, absrt, EE);

  // fused Q+K projection: row n of qk = [q(512) | k(512)]  (N-tile fast in x)
  dim3 gQK(1024/128, (NN+127)/128);
  gemm_bt<<<gQK,256,0,stream>>>(zatt, wqkT, bqk, nullptr, qk, NN, 1024, 512, 512, 0);

  node_att_kernel<<<dim3((NN+3)/4),256,0,stream>>>(qk, rowptr, cols, absrt, pos, xf, NN);

  dim3 gH(1024/128, (NN+127)/128);
  // energy path (h1 overwrites qk — q,k dead after node_att)
  gemm_bt<<<gH,256,0,stream>>>(xf, weIT, beI, nullptr, h1, NN, 1024, 512, 576, 1);
  gemm_bt<<<gH,256,0,stream>>>(h1, weHT, beH, h1,      h2, NN, 1024, 1024, 1024, 1);
  energy_kernel<<<dim3((NN+3)/4),256,0,stream>>>(h2, WeO, beO, (float*)d_out, NN);

  // forces path
  gemm_bt<<<gH,256,0,stream>>>(xf, wfIT, bfI, nullptr, h1, NN, 1024, 576, 576, 1);
  gemm_bt<<<gH,256,0,stream>>>(h1, wfHT, bfH, h1,      h2, NN, 1024, 1024, 1024, 1);
  forces_kernel<<<dim3((NN+3)/4),256,0,stream>>>(h2, WfO, bfO, (float*)d_out + NN, NN);
}

// Round 5
// 638.986 us; speedup vs baseline: 1.1832x; 1.1452x over previous
//
#include <hip/hip_runtime.h>

#define NN 20000
#define EE 600000

typedef unsigned short u16;
typedef unsigned int u32;
typedef float f32x4 __attribute__((ext_vector_type(4)));
typedef u32 u32x4 __attribute__((ext_vector_type(4)));

__device__ __forceinline__ u16 f2bf(float f){
  u32 u = __float_as_uint(f);
  return (u16)((u + 0x7fffu + ((u>>16)&1u))>>16);
}
__device__ __forceinline__ float bf2f(u16 h){ return __uint_as_float(((u32)h)<<16); }

// jax.nn.gelu default (approximate=True, tanh form)
__device__ __forceinline__ float gelu_f(float x){
  float u = 0.7978845608028654f*(x + 0.044715f*x*x*x);
  float e = __expf(2.0f*u);
  return 0.5f*x*(2.0f - 2.0f/(e+1.0f));   // 0.5x(1+tanh(u)), overflow-safe
}

// ---------------------------------------------------------------------------
// LayerNorm x2: za = LN(x;g_att,b_att) (stride 512); z_mlp = LN(x;g_mlp,b_mlp)
// written directly into xf[0:512] (stride 576). One wave per row.
// ---------------------------------------------------------------------------
__global__ __launch_bounds__(256) void ln2_kernel(
    const float* __restrict__ x,
    const float* __restrict__ ga, const float* __restrict__ ba,
    const float* __restrict__ gm, const float* __restrict__ bm,
    u16* __restrict__ za, u16* __restrict__ xf, int N)
{
  int row = (blockIdx.x<<2) + (threadIdx.x>>6);
  int lane = threadIdx.x & 63;
  if(row >= N) return;
  const float* xp = x + ((size_t)row<<9) + (lane<<3);
  f32x4 v0 = *(const f32x4*)xp;
  f32x4 v1 = *(const f32x4*)(xp+4);
  float vals[8] = {v0[0],v0[1],v0[2],v0[3],v1[0],v1[1],v1[2],v1[3]};
  float s=0.f, qs=0.f;
#pragma unroll
  for(int i=0;i<8;i++){ s += vals[i]; qs = fmaf(vals[i],vals[i],qs); }
#pragma unroll
  for(int o=1;o<64;o<<=1){ s += __shfl_xor(s,o); qs += __shfl_xor(qs,o); }
  float mean = s*(1.f/512.f);
  float var  = qs*(1.f/512.f) - mean*mean;
  float rstd = rsqrtf(var + 1e-5f);
  int c0 = lane<<3;
#pragma unroll
  for(int i=0;i<8;i++){
    float zn = (vals[i]-mean)*rstd;
    za[((size_t)row<<9)+c0+i]  = f2bf(fmaf(zn, ga[c0+i], ba[c0+i]));
    xf[(size_t)row*576+c0+i]   = f2bf(fmaf(zn, gm[c0+i], bm[c0+i]));
  }
}

// ---------------------------------------------------------------------------
// Weight transpose via LDS tile: W[K][Nn] fp32 -> WT[Nn][Kpad] bf16, zero pad.
// grid = (Kpad/64, Nn/64), block 256.
// ---------------------------------------------------------------------------
__global__ __launch_bounds__(256) void wtt_kernel(
    const float* __restrict__ W, u16* __restrict__ WT, int K, int Nn, int Kpad)
{
  __shared__ u16 tile[64][65];
  const int k0 = blockIdx.x<<6, n0 = blockIdx.y<<6;
  const int tx = threadIdx.x & 63, ty = threadIdx.x >> 6;
#pragma unroll
  for(int i=0;i<16;i++){
    int r = (i<<2) + ty;                 // k within tile
    int gk = k0 + r;
    float v = (gk < K) ? W[(size_t)gk*Nn + n0 + tx] : 0.f;
    tile[r][tx] = f2bf(v);
  }
  __syncthreads();
#pragma unroll
  for(int i=0;i<16;i++){
    int r = (i<<2) + ty;                 // n within tile
    WT[(size_t)(n0 + r)*Kpad + k0 + tx] = tile[tx][r];
  }
}

// ---------------------------------------------------------------------------
// GEMM: C[M,N] = A[M,K](bf16,row-stride lda) @ B^T[N,K](bf16) + bias.
// 128x128x64 tiles, MFMA 16x16x32, XOR-swizzled LDS, global_load_lds w=16.
// XCD-aware mapping: xcd = b&7, each XCD owns M-tile stripe tileM=(g*8+xcd)
// so all 8 N-blocks of an M-tile run on ONE XCD -> A-tile L2-missed once.
// gridDim.y (M-tiles) must be padded to a multiple of 8; excess blocks exit.
// mode 0: store bf16. mode 1: store gelu(v) bf16.
// mode 2: v = resid + gelu(v); atomicAdd(outp[row], sum_col v*wout[col])  (energy)
// mode 3: same, 3 output channels wout[col*3+c] -> outp[row*3+c]          (forces)
// ---------------------------------------------------------------------------
__global__ __launch_bounds__(256) void gemm_bt(
    const u16* __restrict__ A, const u16* __restrict__ B,
    const float* __restrict__ bias, const u16* __restrict__ resid,
    u16* __restrict__ Cb, const float* __restrict__ wout,
    float* __restrict__ outp,
    int M, int N, int K, int lda, int ldr, int mode)
{
  __shared__ u16 As[128*64];
  __shared__ u16 Bs[128*64];
  const int gx = gridDim.x;
  const int b  = blockIdx.y*gx + blockIdx.x;
  const int xcd = b & 7, loc = b >> 3;
  const int tileM = ((loc/gx)*8 + xcd) << 7;
  const int tileN = (loc % gx) << 7;
  if(tileM >= M) return;
  const int tid  = threadIdx.x;
  const int wave = tid>>6, lane = tid&63;
  const int quad = lane>>4, l15 = lane&15;
  const int mhalf = (wave>>1)<<6, nhalf = (wave&1)<<6;
  f32x4 acc[4][4] = {};

  for(int k0=0; k0<K; k0+=64){
#pragma unroll
    for(int j=0;j<4;j++){
      const int c   = (((wave<<2)+j)<<6) + lane;   // LDS chunk this lane fills
      const int row = c>>3;
      const int cc  = (c&7) ^ (row&7);             // logical k-chunk landing here
      int gr = tileM + row; gr = (gr < M) ? gr : (M-1);
      const u16* gp = A + (size_t)gr*lda + (size_t)(k0 + (cc<<3));
      __builtin_amdgcn_global_load_lds(
        (const __attribute__((address_space(1))) u32*)gp,
        (__attribute__((address_space(3))) u32*)(&As[((wave<<2)+j)<<9]),
        16, 0, 0);
    }
#pragma unroll
    for(int j=0;j<4;j++){
      const int c   = (((wave<<2)+j)<<6) + lane;
      const int row = c>>3;
      const int cc  = (c&7) ^ (row&7);
      const u16* gp = B + (size_t)(tileN + row)*K + (size_t)(k0 + (cc<<3));
      __builtin_amdgcn_global_load_lds(
        (const __attribute__((address_space(1))) u32*)gp,
        (__attribute__((address_space(3))) u32*)(&Bs[((wave<<2)+j)<<9]),
        16, 0, 0);
    }
    __syncthreads();
#pragma unroll
    for(int ks=0;ks<2;ks++){
      const int ccol = (ks<<2) + quad;             // logical 16B k-chunk index
      u32x4 af[4], bfr[4];
#pragma unroll
      for(int mi=0;mi<4;mi++){
        const int row = mhalf + (mi<<4) + l15;
        af[mi] = *(const u32x4*)&As[((row<<3) + (ccol ^ (row&7)))<<3];
      }
#pragma unroll
      for(int ni=0;ni<4;ni++){
        const int row = nhalf + (ni<<4) + l15;
        bfr[ni] = *(const u32x4*)&Bs[((row<<3) + (ccol ^ (row&7)))<<3];
      }
#pragma unroll
      for(int mi=0;mi<4;mi++)
#pragma unroll
        for(int ni=0;ni<4;ni++)
          asm("v_mfma_f32_16x16x32_bf16 %0, %1, %2, %0"
              : "+v"(acc[mi][ni]) : "v"(af[mi]), "v"(bfr[ni]));
    }
    __syncthreads();
  }

  if(mode <= 1){
#pragma unroll
    for(int mi=0;mi<4;mi++){
#pragma unroll
      for(int reg=0;reg<4;reg++){
        const int gr = tileM + mhalf + (mi<<4) + (quad<<2) + reg;
        if(gr < M){
#pragma unroll
          for(int ni=0;ni<4;ni++){
            const int gc = tileN + nhalf + (ni<<4) + l15;
            float v = acc[mi][ni][reg] + bias[gc];
            if(mode == 1) v = gelu_f(v);
            Cb[(size_t)gr*N + gc] = f2bf(v);
          }
        }
      }
    }
  } else if(mode == 2){
    float wv[4], bv[4];
#pragma unroll
    for(int ni=0;ni<4;ni++){
      int gc = tileN + nhalf + (ni<<4) + l15;
      wv[ni] = wout[gc]; bv[ni] = bias[gc];
    }
#pragma unroll
    for(int mi=0;mi<4;mi++){
#pragma unroll
      for(int reg=0;reg<4;reg++){
        const int gr = tileM + mhalf + (mi<<4) + (quad<<2) + reg;
        if(gr < M){
          float vs = 0.f;
#pragma unroll
          for(int ni=0;ni<4;ni++){
            const int gc = tileN + nhalf + (ni<<4) + l15;
            float v = gelu_f(acc[mi][ni][reg] + bv[ni])
                    + bf2f(resid[(size_t)gr*ldr + gc]);
            vs = fmaf(v, wv[ni], vs);
          }
          vs += __shfl_xor(vs,1); vs += __shfl_xor(vs,2);
          vs += __shfl_xor(vs,4); vs += __shfl_xor(vs,8);
          if(l15 == 0) atomicAdd(&outp[gr], vs);
        }
      }
    }
  } else {
    float wv0[4], wv1[4], wv2[4], bv[4];
#pragma unroll
    for(int ni=0;ni<4;ni++){
      int gc = tileN + nhalf + (ni<<4) + l15;
      wv0[ni] = wout[gc*3+0]; wv1[ni] = wout[gc*3+1]; wv2[ni] = wout[gc*3+2];
      bv[ni] = bias[gc];
    }
#pragma unroll
    for(int mi=0;mi<4;mi++){
#pragma unroll
      for(int reg=0;reg<4;reg++){
        const int gr = tileM + mhalf + (mi<<4) + (quad<<2) + reg;
        if(gr < M){
          float s0=0.f, s1=0.f, s2=0.f;
#pragma unroll
          for(int ni=0;ni<4;ni++){
            const int gc = tileN + nhalf + (ni<<4) + l15;
            float v = gelu_f(acc[mi][ni][reg] + bv[ni])
                    + bf2f(resid[(size_t)gr*ldr + gc]);
            s0 = fmaf(v, wv0[ni], s0);
            s1 = fmaf(v, wv1[ni], s1);
            s2 = fmaf(v, wv2[ni], s2);
          }
          s0 += __shfl_xor(s0,1); s0 += __shfl_xor(s0,2); s0 += __shfl_xor(s0,4); s0 += __shfl_xor(s0,8);
          s1 += __shfl_xor(s1,1); s1 += __shfl_xor(s1,2); s1 += __shfl_xor(s1,4); s1 += __shfl_xor(s1,8);
          s2 += __shfl_xor(s2,1); s2 += __shfl_xor(s2,2); s2 += __shfl_xor(s2,4); s2 += __shfl_xor(s2,8);
          if(l15 == 0){
            atomicAdd(&outp[(size_t)gr*3+0], s0);
            atomicAdd(&outp[(size_t)gr*3+1], s1);
            atomicAdd(&outp[(size_t)gr*3+2], s2);
          }
        }
      }
    }
  }
}

// ---------------------------------------------------------------------------
// Output init: energy rows = beO, forces rows = bfO (atomics accumulate on top)
// ---------------------------------------------------------------------------
__global__ __launch_bounds__(256) void out_init_kernel(
    float* __restrict__ out, const float* __restrict__ beO,
    const float* __restrict__ bfO)
{
  int idx = blockIdx.x*256 + threadIdx.x;
  if(idx < NN) out[idx] = beO[0];
  else if(idx < NN*4) out[idx] = bfO[(idx - NN) % 3];
}

// ---------------------------------------------------------------------------
// Edge counting-sort by destination row: histogram, scan, scatter.
// ---------------------------------------------------------------------------
__global__ __launch_bounds__(256) void hist_kernel(
    const int* __restrict__ ei, int* __restrict__ deg, int E)
{
  int e = blockIdx.x*256 + threadIdx.x;
  if(e < E) atomicAdd(&deg[ei[e]], 1);
}

// single-block exclusive scan, shuffle-based (2 barriers per 1024 chunk)
__global__ __launch_bounds__(1024) void scan_kernel(
    const int* __restrict__ deg, int* __restrict__ rowptr,
    int* __restrict__ cursor, int N)
{
  __shared__ int wsum[16];
  __shared__ int carry_s;
  const int tid = threadIdx.x, lane = tid & 63, wid = tid >> 6;
  if(tid == 0) carry_s = 0;
  __syncthreads();
  for(int base = 0; base < N; base += 1024){
    int idx = base + tid;
    int v = (idx < N) ? deg[idx] : 0;
    int s = v;                                   // inclusive wave scan
#pragma unroll
    for(int o=1;o<64;o<<=1){ int t = __shfl_up(s,o); if(lane>=o) s += t; }
    if(lane==63) wsum[wid] = s;
    __syncthreads();
    if(wid==0 && lane<16){
      int ws = wsum[lane];
      int t = ws;
#pragma unroll
      for(int o=1;o<16;o<<=1){ int u = __shfl_up(t,o); if(lane>=o) t += u; }
      wsum[lane] = t - ws;                       // exclusive prefix of wave sums
    }
    __syncthreads();
    int ex = s - v + wsum[wid] + carry_s;
    if(idx < N){ rowptr[idx] = ex; cursor[idx] = ex; }
    __syncthreads();                             // all read carry_s before update
    if(tid == 1023) carry_s += wsum[15] + s;     // total of this chunk
  }
  __syncthreads();
  if(tid == 0) rowptr[N] = carry_s;
}

__global__ __launch_bounds__(256) void scatter_kernel(
    const int* __restrict__ ei, const float* __restrict__ ab,
    int* __restrict__ cursor, int* __restrict__ cols,
    float* __restrict__ abs_, int E)
{
  int e = blockIdx.x*256 + threadIdx.x;
  if(e >= E) return;
  int r = ei[e];
  int p = atomicAdd(&cursor[r], 1);
  cols[p] = ei[EE + e];
  abs_[p] = ab[e];
}

// ---------------------------------------------------------------------------
// Per-node attention: one wave per node. q-row in registers; gather sorted
// k-rows; softmax without max-subtraction (logits O(+-6)); denom & weighted
// pos in registers (no atomics); write att-pos into xf[512:536], 0 -> [536:576].
// 4 edges in flight per iteration. qk row n = [q(512) | k(512)] bf16.
// ---------------------------------------------------------------------------
__global__ __launch_bounds__(256) void node_att_kernel(
    const u16* __restrict__ qk, const int* __restrict__ rowptr,
    const int* __restrict__ cols, const float* __restrict__ abs_,
    const float* __restrict__ pos, u16* __restrict__ xf, int N)
{
  const int node = (blockIdx.x<<2) + (threadIdx.x>>6);
  const int lane = threadIdx.x & 63;
  if(node >= N) return;
  const int h = lane>>3, sub = lane&7;
  const u32x4 qv = *(const u32x4*)(qk + ((size_t)node<<10) + (lane<<3));
  const float posn = (sub<3) ? pos[node*3 + sub] : 0.f;
  const int j1 = rowptr[node+1];
  float den = 0.f, nm = 0.f;

  int j = rowptr[node];
  for(; j+3 < j1; j += 4){
    int c[4]; float abv[4], pv[4]; u32x4 kv[4];
#pragma unroll
    for(int t=0;t<4;t++){ c[t] = cols[j+t]; abv[t] = abs_[j+t]; }
#pragma unroll
    for(int t=0;t<4;t++){
      kv[t] = *(const u32x4*)(qk + ((size_t)c[t]<<10) + 512 + (lane<<3));
      pv[t] = (sub<3) ? pos[c[t]*3+sub] : 0.f;
    }
#pragma unroll
    for(int t=0;t<4;t++){
      float s = 0.f;
#pragma unroll
      for(int i=0;i<4;i++){
        s = fmaf(__uint_as_float(qv[i]<<16),         __uint_as_float(kv[t][i]<<16), s);
        s = fmaf(__uint_as_float(qv[i]&0xffff0000u), __uint_as_float(kv[t][i]&0xffff0000u), s);
      }
      s += __shfl_xor(s,1); s += __shfl_xor(s,2); s += __shfl_xor(s,4);
      float p = __expf(fmaf(s, 0.125f, abv[t]));
      den += p;
      nm = fmaf(p, pv[t], nm);
    }
  }
  for(; j < j1; j++){
    int c0 = cols[j];
    u32x4 kv0 = *(const u32x4*)(qk + ((size_t)c0<<10) + 512 + (lane<<3));
    float pv0 = (sub<3) ? pos[c0*3+sub] : 0.f;
    float s0=0.f;
#pragma unroll
    for(int i=0;i<4;i++){
      s0 = fmaf(__uint_as_float(qv[i]<<16),        __uint_as_float(kv0[i]<<16), s0);
      s0 = fmaf(__uint_as_float(qv[i]&0xffff0000u),__uint_as_float(kv0[i]&0xffff0000u), s0);
    }
    s0 += __shfl_xor(s0,1); s0 += __shfl_xor(s0,2); s0 += __shfl_xor(s0,4);
    float p0 = __expf(fmaf(s0, 0.125f, abs_[j]));
    den += p0;
    nm = fmaf(p0, pv0, nm);
  }

  u16* xp = xf + (size_t)node*576;
  if(sub < 3){
    float a = (den > 0.f) ? nm/den : 0.f;
    xp[512 + h*3 + sub] = f2bf(a - posn);
  } else {
    xp[536 + h*5 + (sub-3)] = 0;   // pad cols 536..575
  }
}

// ---------------------------------------------------------------------------
extern "C" void kernel_launch(void* const* d_in, const int* in_sizes, int n_in,
                              void* d_out, int out_size, void* d_ws, size_t ws_size,
                              hipStream_t stream)
{
  (void)in_sizes; (void)n_in; (void)out_size; (void)ws_size;
  const float* x    = (const float*)d_in[0];
  const int*   ei   = (const int*)d_in[1];
  const float* ab   = (const float*)d_in[2];
  const float* pos  = (const float*)d_in[3];
  const float* g_att= (const float*)d_in[5];
  const float* b_att= (const float*)d_in[6];
  const float* g_mlp= (const float*)d_in[7];
  const float* b_mlp= (const float*)d_in[8];
  const float* Wq   = (const float*)d_in[9];  const float* bq  = (const float*)d_in[10];
  const float* Wk   = (const float*)d_in[11]; const float* bk  = (const float*)d_in[12];
  const float* WeI  = (const float*)d_in[13]; const float* beI = (const float*)d_in[14];
  const float* WeH  = (const float*)d_in[15]; const float* beH = (const float*)d_in[16];
  const float* WeO  = (const float*)d_in[17]; const float* beO = (const float*)d_in[18];
  const float* WfI  = (const float*)d_in[19]; const float* bfI = (const float*)d_in[20];
  const float* WfH  = (const float*)d_in[21]; const float* bfH = (const float*)d_in[22];
  const float* WfO  = (const float*)d_in[23]; const float* bfO = (const float*)d_in[24];

  char* w = (char*)d_ws;
  size_t off = 0;
  auto alloc = [&](size_t bytes) -> void* {
    void* p = w + off; off += (bytes + 255) & ~(size_t)255; return p;
  };
  u16* zatt  = (u16*)alloc((size_t)NN*512*2);
  u16* qk    = (u16*)alloc((size_t)NN*1024*2);   // [q|k] per row
  u16* xf    = (u16*)alloc((size_t)NN*576*2);    // [z_mlp(512)|att(24)|0(40)]
  u16* h1cat = (u16*)alloc((size_t)NN*2048*2);   // [h1_energy(1024)|h1_forces(1024)]
  u16* wqkT  = (u16*)alloc((size_t)1024*512*2);
  u16* wInT  = (u16*)alloc((size_t)2048*576*2);  // [WeI_T pad576 | WfI_T]
  u16* weHT  = (u16*)alloc((size_t)1024*1024*2);
  u16* wfHT  = (u16*)alloc((size_t)1024*1024*2);
  float* bqk    = (float*)alloc((size_t)1024*4);
  float* bcat   = (float*)alloc((size_t)2048*4);
  int*   deg    = (int*)alloc((size_t)NN*4);
  int*   rowptr = (int*)alloc((size_t)(NN+1)*4);
  int*   cursor = (int*)alloc((size_t)NN*4);
  int*   cols   = (int*)alloc((size_t)EE*4);
  float* absrt  = (float*)alloc((size_t)EE*4);

  hipMemsetAsync(deg, 0, (size_t)NN*4, stream);
  hipMemcpyAsync(bqk,        bq,  512*4, hipMemcpyDeviceToDevice, stream);
  hipMemcpyAsync(bqk + 512,  bk,  512*4, hipMemcpyDeviceToDevice, stream);
  hipMemcpyAsync(bcat,       beI, 1024*4, hipMemcpyDeviceToDevice, stream);
  hipMemcpyAsync(bcat + 1024,bfI, 1024*4, hipMemcpyDeviceToDevice, stream);

  // weights -> bf16 transposed [N][Kpad]
  wtt_kernel<<<dim3(512/64, 512/64),256,0,stream>>>(Wq, wqkT,           512, 512, 512);
  wtt_kernel<<<dim3(512/64, 512/64),256,0,stream>>>(Wk, wqkT + 512*512, 512, 512, 512);
  wtt_kernel<<<dim3(576/64, 1024/64),256,0,stream>>>(WeI, wInT,              512, 1024, 576);
  wtt_kernel<<<dim3(576/64, 1024/64),256,0,stream>>>(WfI, wInT + 1024*576,   536, 1024, 576);
  wtt_kernel<<<dim3(1024/64,1024/64),256,0,stream>>>(WeH, weHT, 1024, 1024, 1024);
  wtt_kernel<<<dim3(1024/64,1024/64),256,0,stream>>>(WfH, wfHT, 1024, 1024, 1024);

  out_init_kernel<<<dim3((NN*4+255)/256),256,0,stream>>>((float*)d_out, beO, bfO);

  ln2_kernel<<<dim3((NN+3)/4),256,0,stream>>>(x, g_att,b_att, g_mlp,b_mlp, zatt, xf, NN);

  // counting sort of edges by destination (row) node
  hist_kernel   <<<dim3((EE+255)/256),256,0,stream>>>(ei, deg, EE);
  scan_kernel   <<<1,1024,0,stream>>>(deg, rowptr, cursor, NN);
  scatter_kernel<<<dim3((EE+255)/256),256,0,stream>>>(ei, ab, cursor, cols, absrt, EE);

  const int MT = 160;  // 157 M-tiles padded to multiple of 8 (XCD stripes)

  // fused Q+K projection: row n of qk = [q(512) | k(512)]
  gemm_bt<<<dim3(8, MT),256,0,stream>>>(zatt, wqkT, bqk, nullptr, qk,
                                        nullptr, nullptr, NN, 1024, 512, 512, 0, 0);

  node_att_kernel<<<dim3((NN+3)/4),256,0,stream>>>(qk, rowptr, cols, absrt, pos, xf, NN);

  // fused in-projections: h1cat = gelu(xf @ [WeI(pad)|WfI] + bcat), N=2048
  gemm_bt<<<dim3(16, MT),256,0,stream>>>(xf, wInT, bcat, nullptr, h1cat,
                                         nullptr, nullptr, NN, 2048, 576, 576, 0, 1);

  // hidden GEMMs with fused residual + out-projection (atomicAdd into d_out)
  gemm_bt<<<dim3(8, MT),256,0,stream>>>(h1cat, weHT, beH, h1cat, nullptr,
                                        WeO, (float*)d_out,
                                        NN, 1024, 1024, 2048, 2048, 2);
  gemm_bt<<<dim3(8, MT),256,0,stream>>>(h1cat+1024, wfHT, bfH, h1cat+1024, nullptr,
                                        WfO, (float*)d_out + NN,
                                        NN, 1024, 1024, 2048, 2048, 3);
}